// Round 5
// baseline (684.103 us; speedup 1.0000x reference)
//
#include <hip/hip_runtime.h>
#include <hip/hip_bf16.h>

// ScaleNet gated residual block, MI355X — bf16 MFMA implicit GEMM.
//  K0w wcvt       : mask weights f32 -> f64, layout [c][mask(2)][tap(9)]
//  K0a mask_part  : tap-decomposed channel reduction -> z partials (f64, ws)
//  K0b mask_reduce: 9-point stencil sum of z + bias, threshold -> m1, m2
//  K1 transpose   : x NCHW f32 -> xb NHWC bf16 (stored in d_out scratch)
//  K2 pack        : w1,w2 OIHW f32 -> B-frag-ready packed bf16
//  K3 conv_mfma<1>: conv1 + BN1 + ReLU + *m1 -> tmp NHWC bf16 (ws)
//  K4 conv_mfma<0>: conv2 + BN2 + *m2 + residual + ReLU -> d_out NCHW f32
//
// R5: 2-block residency never materialized (Occ 15.7%, 25% ceiling across
//     rounds). Force 8 waves/CU structurally: 512-thread block, 8 waves =
//     2(subtile) x 4(co-group). Wave = 64px x 64co -> acc 64 AGPR, ~155
//     total regs. A-reads/wave halve (own subtile). XCD-chunked swizzle.

#define NB 32
#define C  256
#define H  56
#define W  56
#define HW (H*W)          // 3136 = 49*64
#define NBHW (NB*HW)      // 100352
#define EPSV 1e-5f
#define WELEM (C*C*9)     // 589824 packed elements per conv
#define MSPL 2            // mask split-K over channels
#define MCH (C/MSPL)      // 128 channels per split

typedef __hip_bfloat16 bf16;
typedef __attribute__((ext_vector_type(8))) short  bf16x8;
typedef __attribute__((ext_vector_type(4))) float  floatx4;

// ---------------- K0w: mask weights f32 -> f64 ------------------------------
__global__ __launch_bounds__(128) void wcvt_kernel(
    const float* __restrict__ wm1, const float* __restrict__ wm2,
    double* __restrict__ wd)
{
    int i = blockIdx.x * 128 + threadIdx.x;   // 0 .. C*18-1
    if (i >= C * 18) return;
    int c = i / 18;
    int r = i - c * 18;
    int m = r / 9;
    int t = r - 9 * m;
    const float* src = m ? wm2 : wm1;
    wd[i] = (double)src[c * 9 + t];
}

// ---------------- K0a: tap-decomposed mask partials -------------------------
__global__ __launch_bounds__(128) void mask_part_kernel(
    const float* __restrict__ x, const double* __restrict__ wd,
    double* __restrict__ z)
{
    int pixb  = blockIdx.x >> 1;              // 784 pixel-blocks of 128
    int split = blockIdx.x & 1;
    int idx = pixb * 128 + threadIdx.x;       // pixel id, exact (100352 total)
    int n  = idx / HW;
    int hw = idx - n * HW;

    const float*  xp = x  + (size_t)n * C * HW + (size_t)split * MCH * HW + hw;
    const double* wp = wd + (size_t)split * MCH * 18;

    double acc[18];
    #pragma unroll
    for (int j = 0; j < 18; ++j) acc[j] = 0.0;

    for (int c = 0; c < MCH; ++c) {
        double xv = (double)xp[(size_t)c * HW];   // coalesced across lanes
        const double* w = wp + c * 18;            // wave-uniform -> s_load
        #pragma unroll
        for (int j = 0; j < 18; ++j)
            acc[j] += xv * w[j];
    }

    #pragma unroll
    for (int j = 0; j < 18; ++j)
        z[(size_t)(split * 18 + j) * NBHW + idx] = acc[j];
}

// ---------------- K0b: stencil-sum partials, threshold ----------------------
__global__ __launch_bounds__(256) void mask_reduce_kernel(
    const double* __restrict__ z,
    const float* __restrict__ bm1, const float* __restrict__ bm2,
    float* __restrict__ m1, float* __restrict__ m2)
{
    int idx = blockIdx.x * 256 + threadIdx.x;
    int n  = idx / HW;
    int hw = idx - n * HW;
    int h  = hw / W;
    int w_ = hw - h * W;

    double a1 = (double)bm1[0], a2 = (double)bm2[0];
    #pragma unroll
    for (int ky = 0; ky < 3; ++ky) {
        int y = h + ky - 1;
        if ((unsigned)y >= (unsigned)H) continue;
        #pragma unroll
        for (int kx = 0; kx < 3; ++kx) {
            int xx = w_ + kx - 1;
            if ((unsigned)xx >= (unsigned)W) continue;
            int t = ky * 3 + kx;
            size_t q = (size_t)n * HW + (size_t)y * W + xx;
            a1 += z[(size_t)(0 * 18 + 0 * 9 + t) * NBHW + q]
                + z[(size_t)(1 * 18 + 0 * 9 + t) * NBHW + q];
            a2 += z[(size_t)(0 * 18 + 1 * 9 + t) * NBHW + q]
                + z[(size_t)(1 * 18 + 1 * 9 + t) * NBHW + q];
        }
    }
    m1[idx] = (a1 > 0.0) ? 1.0f : 0.0f;   // sigmoid(z)>0.5 <=> z>0
    m2[idx] = (a2 > 0.0) ? 1.0f : 0.0f;
}

// ---------------- K1: NCHW f32 -> NHWC bf16 ---------------------------------
__global__ __launch_bounds__(256) void transpose_kernel(
    const float* __restrict__ x, bf16* __restrict__ xb)
{
    __shared__ float tile[64][65];
    int bid = blockIdx.x;             // 32 * 4 * 49
    int pt = bid % 49; bid /= 49;
    int ct = bid % 4;  int n = bid / 4;
    int p0 = pt * 64, c0 = ct * 64;
    int tl = threadIdx.x & 63;
    int tg = threadIdx.x >> 6;        // 0..3
    const float* xp = x + ((size_t)(n*C + c0) * HW) + p0;
    #pragma unroll
    for (int i = 0; i < 16; ++i) {
        int cl = tg*16 + i;
        tile[cl][tl] = xp[(size_t)cl * HW + tl];
    }
    __syncthreads();
    bf16* op = xb + ((size_t)(n*HW + p0) * C) + c0;
    #pragma unroll
    for (int i = 0; i < 16; ++i) {
        int pl = tg*16 + i;
        op[(size_t)pl * C + tl] = __float2bfloat16(tile[tl][pl]);
    }
}

// ---------------- K2: pack weights into B-frag order ------------------------
// layout: [tap(9)][kstep(8)][ntile(16)][lane(64)][8 ci]  (16B per lane)
__global__ __launch_bounds__(256) void pack_kernel(
    const float* __restrict__ w1, const float* __restrict__ w2,
    bf16* __restrict__ w1p, bf16* __restrict__ w2p)
{
    int idx = blockIdx.x * 256 + threadIdx.x;       // 0 .. 2*WELEM-1
    const float* src = (idx < WELEM) ? w1 : w2;
    bf16* dst        = (idx < WELEM) ? w1p : w2p;
    int f = (idx < WELEM) ? idx : idx - WELEM;
    int e  = f & 7;
    int O  = f >> 3;
    int L  = O & 63;
    int j  = (O >> 6) & 15;
    int ks = (O >> 10) & 7;
    int t  = O >> 13;
    int co = j*16 + (L & 15);
    int ci = ks*32 + ((L >> 4) & 3)*8 + e;
    dst[f] = __float2bfloat16(src[((size_t)co*C + ci)*9 + t]);
}

// ---------------- K3/K4: MFMA implicit-GEMM conv ----------------------------
// block: 512 thr = 8 waves = 2(subtile) x 4(co-group). 128 px x 256 co.
// Per wave per gs: 4 B global loads, 4 A ds_reads, 16 MFMA. A+B 1-gs
// register-double-buffered; gs loop unroll(4) so rotation is renaming.
template<bool FIRST>
__global__ __launch_bounds__(512, 1) void conv_mfma(
    const bf16* __restrict__ inb,    // NHWC bf16
    const bf16* __restrict__ wp,     // packed weights
    const float* __restrict__ g,  const float* __restrict__ b,
    const float* __restrict__ mu, const float* __restrict__ vv,
    const float* __restrict__ mask,  // [NB][HW] 0/1
    const float* __restrict__ xres,  // NCHW f32 (SECOND)
    bf16* __restrict__ outb,         // FIRST: tmp NHWC bf16
    float* __restrict__ outf)        // SECOND: NCHW f32
{
    __shared__ uint4 patch4[3400];   // 2 subtiles * 100 pos * 17 uint4 = 54.4 KB
    __shared__ float msk[128];
    short* patch = (short*)patch4;

    int tid = threadIdx.x;
    int L   = tid & 63;
    int wv  = tid >> 6;              // 0..7
    int wr  = wv >> 2;               // subtile 0/1
    int wc  = wv & 3;                // co-group (64 co)

    int bid = (int)blockIdx.x;
    bid = (bid & 7) * 98 + (bid >> 3);   // XCD-chunked swizzle (784 = 8*98)

    // two flattened (n,tile) ids
    int t0g = bid * 2;
    int n_s[2], y0_s[2], x0_s[2];
    size_t ibase_s[2];
    #pragma unroll
    for (int s = 0; s < 2; ++s) {
        int ts = t0g + s;
        int ns = ts / 49;
        int tl = ts - ns * 49;
        n_s[s]  = ns;
        y0_s[s] = (tl / 7) * 8;
        x0_s[s] = (tl % 7) * 8;
        ibase_s[s] = (size_t)ns * HW * C;
    }

    if (tid < 128) {
        int s  = tid >> 6;
        int p  = tid & 63;
        int pr = p >> 3, pc = p & 7;
        msk[tid] = mask[(size_t)n_s[s]*HW + (y0_s[s]+pr)*W + (x0_s[s]+pc)];
    }

    // per-lane A-fragment base offsets, OWN subtile only
    // (padded stride 136 shorts/position; subtile stride 13600 shorts)
    int m  = L & 15;
    int kb = L >> 4;
    int abase[4];
    #pragma unroll
    for (int mi = 0; mi < 4; ++mi) {
        int p   = mi*16 + m;          // 0..63 within subtile
        int pos = (p >> 3)*10 + (p & 7);
        abase[mi] = wr*13600 + pos*136 + kb*8;
    }

    // per-lane/per-wave B base (elements): lane 16B chunk + co-group offset
    const bf16* wpw = wp + (size_t)L*8 + (size_t)wc*4*512;

    floatx4 acc[4][4];
    #pragma unroll
    for (int mi = 0; mi < 4; ++mi)
        #pragma unroll
        for (int jj = 0; jj < 4; ++jj)
            acc[mi][jj] = (floatx4){0.f, 0.f, 0.f, 0.f};

    for (int ck = 0; ck < 2; ++ck) {
        if (ck) __syncthreads();                 // LDS reuse fence
        // ---- stage two 10x10 halo patches, 128-ci chunk, into LDS ----
        for (int S = tid; S < 3200; S += 512) {
            int s   = S >= 1600;
            int r0  = S - s*1600;
            int q   = r0 & 15;
            int pos = r0 >> 4;
            int rr = pos / 10, cc = pos - (pos/10)*10;
            int y  = y0_s[s] + rr - 1;
            int xx = x0_s[s] + cc - 1;
            uint4 val = make_uint4(0u, 0u, 0u, 0u);
            if ((unsigned)y < (unsigned)H && (unsigned)xx < (unsigned)W)
                val = *(const uint4*)(inb + ibase_s[s] + (size_t)(y*W + xx)*C + ck*128 + q*8);
            patch4[s*1700 + pos*17 + q] = val;
        }
        __syncthreads();

        // ---- K-loop: 9 taps x 4 ksteps, A+B register-double-buffered ----
        bf16x8 bcur[4], bnxt[4];
        bf16x8 acur[4], anxt[4];
        {
            const bf16* bp = wpw + (size_t)(0*8 + ck*4) * 8192;
            #pragma unroll
            for (int jj = 0; jj < 4; ++jj)
                bcur[jj] = *(const bf16x8*)(bp + jj*512);
            #pragma unroll
            for (int mi = 0; mi < 4; ++mi)
                acur[mi] = *(const bf16x8*)(patch + abase[mi]);   // gs=0: aoff=0
        }
        #pragma unroll 4
        for (int gs = 0; gs < 36; ++gs) {
            if (gs < 35) {
                int g2 = gs + 1;
                int t2 = g2 >> 2, s2 = g2 & 3;
                const bf16* bp = wpw + (size_t)(t2*8 + ck*4 + s2) * 8192;
                #pragma unroll
                for (int jj = 0; jj < 4; ++jj)
                    bnxt[jj] = *(const bf16x8*)(bp + jj*512);
                int ky2 = t2 / 3;
                int dt2 = ky2*10 + (t2 - ky2*3);
                int aoff2 = dt2*136 + s2*32;
                #pragma unroll
                for (int mi = 0; mi < 4; ++mi)
                    anxt[mi] = *(const bf16x8*)(patch + abase[mi] + aoff2);
            }
            #pragma unroll
            for (int mi = 0; mi < 4; ++mi)
                #pragma unroll
                for (int jj = 0; jj < 4; ++jj)
                    acc[mi][jj] = __builtin_amdgcn_mfma_f32_16x16x32_bf16(
                        acur[mi], bcur[jj], acc[mi][jj], 0, 0, 0);
            #pragma unroll
            for (int jj = 0; jj < 4; ++jj) bcur[jj] = bnxt[jj];
            #pragma unroll
            for (int mi = 0; mi < 4; ++mi) acur[mi] = anxt[mi];
        }
    }

    // ---- epilogue: wave writes its 64co x own 64-px subtile ----
    int quad  = L >> 4;
    int s     = wr;
    #pragma unroll
    for (int jj = 0; jj < 4; ++jj) {
        int co = wc*64 + jj*16 + (L & 15);
        float s_ = g[co] * rsqrtf(vv[co] + EPSV);
        float t_ = b[co] - mu[co] * s_;
        #pragma unroll
        for (int mi = 0; mi < 4; ++mi) {
            int pl = mi*16 + quad*4;          // 0..63 within subtile
            if (FIRST) {
                #pragma unroll
                for (int r = 0; r < 4; ++r) {
                    int p = pl + r;
                    float v = acc[mi][jj][r] * s_ + t_;
                    v = fmaxf(v, 0.f) * msk[s*64 + p];
                    int pg = (y0_s[s] + (p >> 3))*W + (x0_s[s] + (p & 7));
                    outb[ibase_s[s] + (size_t)pg*C + co] = __float2bfloat16(v);
                }
            } else {
                int pg = (y0_s[s] + (pl >> 3))*W + (x0_s[s] + (pl & 7));
                size_t oidx = ((size_t)(n_s[s]*C + co))*HW + pg;
                floatx4 xr = *(const floatx4*)(xres + oidx);
                floatx4 ov;
                #pragma unroll
                for (int r = 0; r < 4; ++r) {
                    float v = acc[mi][jj][r] * s_ + t_;
                    v = v * msk[s*64 + pl + r] + xr[r];
                    ov[r] = fmaxf(v, 0.f);
                }
                *(floatx4*)(outf + oidx) = ov;
            }
        }
    }
}

extern "C" void kernel_launch(void* const* d_in, const int* in_sizes, int n_in,
                              void* d_out, int out_size, void* d_ws, size_t ws_size,
                              hipStream_t stream) {
    const float* x   = (const float*)d_in[0];
    const float* w1  = (const float*)d_in[1];
    const float* w2  = (const float*)d_in[2];
    const float* g1  = (const float*)d_in[3];
    const float* b1  = (const float*)d_in[4];
    const float* mu1 = (const float*)d_in[5];
    const float* v1  = (const float*)d_in[6];
    const float* g2  = (const float*)d_in[7];
    const float* b2  = (const float*)d_in[8];
    const float* mu2 = (const float*)d_in[9];
    const float* v2  = (const float*)d_in[10];
    const float* wm1 = (const float*)d_in[11];
    const float* bm1 = (const float*)d_in[12];
    const float* wm2 = (const float*)d_in[13];
    const float* bm2 = (const float*)d_in[14];
    float* out = (float*)d_out;

    // workspace (~83.5 MB):
    float* m1   = (float*)d_ws;                      // NB*HW
    float* m2   = m1 + (size_t)NBHW;                 // NB*HW
    bf16*  w1p  = (bf16*)(m2 + (size_t)NBHW);        // WELEM
    bf16*  w2p  = w1p + WELEM;                       // WELEM
    bf16*  tmpb = w2p + WELEM;                       // NB*HW*C bf16
    double* z   = (double*)(tmpb + (size_t)NBHW*C);  // MSPL*2*9*NBHW f64 = 28.9 MB
    double* wd  = z + (size_t)MSPL*18*NBHW;          // C*18 f64
    // xb (NHWC bf16, 51.4 MB) lives in d_out: dead until conv2's epilogue.
    bf16*  xb   = (bf16*)d_out;

    wcvt_kernel<<<(C*18 + 127)/128, 128, 0, stream>>>(wm1, wm2, wd);
    mask_part_kernel<<<(NBHW/128)*MSPL, 128, 0, stream>>>(x, wd, z);
    mask_reduce_kernel<<<NBHW/256, 256, 0, stream>>>(z, bm1, bm2, m1, m2);
    transpose_kernel<<<NB*4*49, 256, 0, stream>>>(x, xb);
    pack_kernel<<<2*WELEM/256, 256, 0, stream>>>(w1, w2, w1p, w2p);

    const int grid = NBHW / 128;    // 784 blocks: two 8x8 subtiles x full co
    conv_mfma<true ><<<grid, 512, 0, stream>>>(
        xb,   w1p, g1, b1, mu1, v1, m1, nullptr, tmpb, nullptr);
    conv_mfma<false><<<grid, 512, 0, stream>>>(
        tmpb, w2p, g2, b2, mu2, v2, m2, x, nullptr, out);
}

// Round 6
// 603.073 us; speedup vs baseline: 1.1344x; 1.1344x over previous
//
#include <hip/hip_runtime.h>
#include <hip/hip_bf16.h>

// ScaleNet gated residual block, MI355X — bf16 MFMA implicit GEMM.
//  K0w wcvt       : mask weights f32 -> f64, layout [c][mask(2)][tap(9)]
//  K0a mask_part  : tap-decomposed channel reduction -> z partials (f64, ws)
//  K0b mask_reduce: 9-point stencil sum of z + bias, threshold -> m1, m2
//  K1 transpose   : x NCHW f32 -> xb NHWC bf16 (stored in d_out scratch)
//  K2 pack        : w1,w2 OIHW f32 -> B-frag-ready packed bf16
//  K3 conv_mfma<1>: conv1 + BN1 + ReLU + *m1 -> tmp NHWC bf16 (ws)
//  K4 conv_mfma<0>: conv2 + BN2 + *m2 + residual + ReLU -> d_out NCHW f32
//
// R6: B-from-global in the K-loop is the 5-round-invariant stall (MfmaUtil
//     ~25%). m97 restructure: B staged to LDS dbuf via async global_load_lds
//     (width 16), 72 stages of BK=32 (8 ci-chunks x 9 taps), 2-barrier
//     cadence, A patch in conflict-free granule layout. R4 geometry kept
//     (256 thr, 128px x 256co, 784 blocks, XCD swizzle). LDS 45 KB ->
//     2 blocks/CU co-resident.

#define NB 32
#define C  256
#define H  56
#define W  56
#define HW (H*W)          // 3136 = 49*64
#define NBHW (NB*HW)      // 100352
#define EPSV 1e-5f
#define WELEM (C*C*9)     // 589824 packed elements per conv
#define MSPL 2            // mask split-K over channels
#define MCH (C/MSPL)      // 128 channels per split

typedef __hip_bfloat16 bf16;
typedef __attribute__((ext_vector_type(8))) short  bf16x8;
typedef __attribute__((ext_vector_type(4))) float  floatx4;

// async 16B/lane global->LDS DMA: lds gets wave-uniform base + lane*16
__device__ __forceinline__ void async_copy16(void* lds, const void* gptr) {
    __builtin_amdgcn_global_load_lds(
        (const __attribute__((address_space(1))) unsigned int*)gptr,
        (__attribute__((address_space(3))) unsigned int*)lds, 16, 0, 0);
}

// ---------------- K0w: mask weights f32 -> f64 ------------------------------
__global__ __launch_bounds__(128) void wcvt_kernel(
    const float* __restrict__ wm1, const float* __restrict__ wm2,
    double* __restrict__ wd)
{
    int i = blockIdx.x * 128 + threadIdx.x;   // 0 .. C*18-1
    if (i >= C * 18) return;
    int c = i / 18;
    int r = i - c * 18;
    int m = r / 9;
    int t = r - 9 * m;
    const float* src = m ? wm2 : wm1;
    wd[i] = (double)src[c * 9 + t];
}

// ---------------- K0a: tap-decomposed mask partials -------------------------
__global__ __launch_bounds__(128) void mask_part_kernel(
    const float* __restrict__ x, const double* __restrict__ wd,
    double* __restrict__ z)
{
    int pixb  = blockIdx.x >> 1;              // 784 pixel-blocks of 128
    int split = blockIdx.x & 1;
    int idx = pixb * 128 + threadIdx.x;       // pixel id, exact (100352 total)
    int n  = idx / HW;
    int hw = idx - n * HW;

    const float*  xp = x  + (size_t)n * C * HW + (size_t)split * MCH * HW + hw;
    const double* wp = wd + (size_t)split * MCH * 18;

    double acc[18];
    #pragma unroll
    for (int j = 0; j < 18; ++j) acc[j] = 0.0;

    for (int c = 0; c < MCH; ++c) {
        double xv = (double)xp[(size_t)c * HW];   // coalesced across lanes
        const double* w = wp + c * 18;            // wave-uniform -> s_load
        #pragma unroll
        for (int j = 0; j < 18; ++j)
            acc[j] += xv * w[j];
    }

    #pragma unroll
    for (int j = 0; j < 18; ++j)
        z[(size_t)(split * 18 + j) * NBHW + idx] = acc[j];
}

// ---------------- K0b: stencil-sum partials, threshold ----------------------
__global__ __launch_bounds__(256) void mask_reduce_kernel(
    const double* __restrict__ z,
    const float* __restrict__ bm1, const float* __restrict__ bm2,
    float* __restrict__ m1, float* __restrict__ m2)
{
    int idx = blockIdx.x * 256 + threadIdx.x;
    int n  = idx / HW;
    int hw = idx - n * HW;
    int h  = hw / W;
    int w_ = hw - h * W;

    double a1 = (double)bm1[0], a2 = (double)bm2[0];
    #pragma unroll
    for (int ky = 0; ky < 3; ++ky) {
        int y = h + ky - 1;
        if ((unsigned)y >= (unsigned)H) continue;
        #pragma unroll
        for (int kx = 0; kx < 3; ++kx) {
            int xx = w_ + kx - 1;
            if ((unsigned)xx >= (unsigned)W) continue;
            int t = ky * 3 + kx;
            size_t q = (size_t)n * HW + (size_t)y * W + xx;
            a1 += z[(size_t)(0 * 18 + 0 * 9 + t) * NBHW + q]
                + z[(size_t)(1 * 18 + 0 * 9 + t) * NBHW + q];
            a2 += z[(size_t)(0 * 18 + 1 * 9 + t) * NBHW + q]
                + z[(size_t)(1 * 18 + 1 * 9 + t) * NBHW + q];
        }
    }
    m1[idx] = (a1 > 0.0) ? 1.0f : 0.0f;   // sigmoid(z)>0.5 <=> z>0
    m2[idx] = (a2 > 0.0) ? 1.0f : 0.0f;
}

// ---------------- K1: NCHW f32 -> NHWC bf16 ---------------------------------
__global__ __launch_bounds__(256) void transpose_kernel(
    const float* __restrict__ x, bf16* __restrict__ xb)
{
    __shared__ float tile[64][65];
    int bid = blockIdx.x;             // 32 * 4 * 49
    int pt = bid % 49; bid /= 49;
    int ct = bid % 4;  int n = bid / 4;
    int p0 = pt * 64, c0 = ct * 64;
    int tl = threadIdx.x & 63;
    int tg = threadIdx.x >> 6;        // 0..3
    const float* xp = x + ((size_t)(n*C + c0) * HW) + p0;
    #pragma unroll
    for (int i = 0; i < 16; ++i) {
        int cl = tg*16 + i;
        tile[cl][tl] = xp[(size_t)cl * HW + tl];
    }
    __syncthreads();
    bf16* op = xb + ((size_t)(n*HW + p0) * C) + c0;
    #pragma unroll
    for (int i = 0; i < 16; ++i) {
        int pl = tg*16 + i;
        op[(size_t)pl * C + tl] = __float2bfloat16(tile[tl][pl]);
    }
}

// ---------------- K2: pack weights into B-frag order ------------------------
// layout: [tap(9)][kstep(8)][ntile(16)][lane(64)][8 ci]  (16B per lane)
__global__ __launch_bounds__(256) void pack_kernel(
    const float* __restrict__ w1, const float* __restrict__ w2,
    bf16* __restrict__ w1p, bf16* __restrict__ w2p)
{
    int idx = blockIdx.x * 256 + threadIdx.x;       // 0 .. 2*WELEM-1
    const float* src = (idx < WELEM) ? w1 : w2;
    bf16* dst        = (idx < WELEM) ? w1p : w2p;
    int f = (idx < WELEM) ? idx : idx - WELEM;
    int e  = f & 7;
    int O  = f >> 3;
    int L  = O & 63;
    int j  = (O >> 6) & 15;
    int ks = (O >> 10) & 7;
    int t  = O >> 13;
    int co = j*16 + (L & 15);
    int ci = ks*32 + ((L >> 4) & 3)*8 + e;
    dst[f] = __float2bfloat16(src[((size_t)co*C + ci)*9 + t]);
}

// ---------------- K3/K4: MFMA implicit-GEMM conv ----------------------------
// 256 thr / 4 waves; 128 px (two 8x8 subtiles) x 256 co per block.
// 72 stages (8 ci-chunks x 9 taps), BK=32. Per stage:
//   issue next B tile (16 KB) -> LDS dbuf via 4x global_load_lds(16B)/thread
//   compute 8 A ds_read + 4 B ds_read + 32 MFMA from current buffers
//   __syncthreads() (drains vmcnt -> next B landed), flip.
// A patch granule layout [kbg][pos2][8ci]: linear 16B granules, ~conflict-free.
template<bool FIRST>
__global__ __launch_bounds__(256, 2) void conv_mfma(
    const bf16* __restrict__ inb,    // NHWC bf16
    const bf16* __restrict__ wp,     // packed weights
    const float* __restrict__ g,  const float* __restrict__ b,
    const float* __restrict__ mu, const float* __restrict__ vv,
    const float* __restrict__ mask,  // [NB][HW] 0/1
    const float* __restrict__ xres,  // NCHW f32 (SECOND)
    bf16* __restrict__ outb,         // FIRST: tmp NHWC bf16
    float* __restrict__ outf)        // SECOND: NCHW f32
{
    __shared__ uint4 albufq[800];        // A granules: 12.8 KB
    __shared__ uint4 bbufq[2][1024];     // B dbuf: 2 x 16 KB
    __shared__ float msk[128];
    short* albuf = (short*)albufq;

    int tid = threadIdx.x;
    int L   = tid & 63;
    int wv  = tid >> 6;              // 0..3 co-group

    int bid = (int)blockIdx.x;
    bid = (bid & 7) * 98 + (bid >> 3);   // XCD-chunked swizzle (784 = 8*98)

    int t0g = bid * 2;
    int n0 = t0g / 49, tl0 = t0g - n0 * 49;
    int y0a = (tl0 / 7) * 8, x0a = (tl0 % 7) * 8;
    size_t ibasea = (size_t)n0 * HW * C;
    int t1g = t0g + 1;
    int n1 = t1g / 49, tl1 = t1g - n1 * 49;
    int y0b = (tl1 / 7) * 8, x0b = (tl1 % 7) * 8;
    size_t ibaseb = (size_t)n1 * HW * C;

    if (tid < 128) {
        int s  = tid >> 6;
        int p  = tid & 63;
        int pr = p >> 3, pc = p & 7;
        int nn = s ? n1  : n0;
        int yy = s ? y0b : y0a;
        int xx = s ? x0b : x0a;
        msk[tid] = mask[(size_t)nn*HW + (yy+pr)*W + (xx+pc)];
    }

    // A-frag base addresses (shorts): granule (kb, pos2), tap adds dt*8
    int m  = L & 15;
    int kb = L >> 4;
    int a_addr[8];
    #pragma unroll
    for (int mi = 0; mi < 8; ++mi) {
        int p    = mi*16 + m;            // 0..127
        int sub  = p >> 6;
        int pl   = p & 63;
        int pos2 = sub*100 + (pl >> 3)*10 + (pl & 7);
        a_addr[mi] = (kb*200 + pos2) * 8;
    }
    // B-frag addresses (shorts) within a 16 KB stage buffer
    int b_addr[4];
    #pragma unroll
    for (int jj = 0; jj < 4; ++jj)
        b_addr[jj] = ((wv*4 + jj)*64 + L) * 8;

    floatx4 acc[8][4];
    #pragma unroll
    for (int mi = 0; mi < 8; ++mi)
        #pragma unroll
        for (int jj = 0; jj < 4; ++jj)
            acc[mi][jj] = (floatx4){0.f, 0.f, 0.f, 0.f};

    // ---- staging helpers ----
    auto stageA = [&](int ck) {
        for (int S = tid; S < 800; S += 256) {
            int kbg  = S / 200;              // ci granule 0..3
            int pos2 = S - kbg*200;
            int sub  = pos2 >= 100;
            int pos  = sub ? pos2 - 100 : pos2;
            int r  = pos / 10;
            int c  = pos - r*10;
            int yy = (sub ? y0b : y0a) + r - 1;
            int xx = (sub ? x0b : x0a) + c - 1;
            uint4 val = make_uint4(0u, 0u, 0u, 0u);
            if ((unsigned)yy < (unsigned)H && (unsigned)xx < (unsigned)W) {
                size_t ib = sub ? ibaseb : ibasea;
                val = *(const uint4*)(inb + ib + (size_t)(yy*W + xx)*C + ck*32 + kbg*8);
            }
            albufq[S] = val;
        }
    };
    auto issueB = [&](int tap, int ck, int buf) {
        const bf16* src = wp + (size_t)(tap*8 + ck) * 8192;
        short* dstb = (short*)bbufq[buf];
        #pragma unroll
        for (int i = 0; i < 4; ++i) {
            int off = (wv*4 + i) * 512;      // elements; wave-uniform
            async_copy16(dstb + off, src + off + L*8);
        }
    };

    // prologue
    stageA(0);
    issueB(0, 0, 0);
    __syncthreads();

    int cur = 0;
    for (int ck = 0; ck < 8; ++ck) {
        #pragma unroll
        for (int tap = 0; tap < 9; ++tap) {
            // prefetch next stage's B into the other buffer
            if (tap < 8)          issueB(tap + 1, ck,     cur ^ 1);
            else if (ck < 7)      issueB(0,       ck + 1, cur ^ 1);

            // compute from current buffers
            const int ky = tap / 3;
            const int aoff = (ky*10 + (tap - ky*3)) * 8;   // dt*8 shorts
            short* bb = (short*)bbufq[cur];
            bf16x8 af[8], bfr[4];
            #pragma unroll
            for (int mi = 0; mi < 8; ++mi)
                af[mi] = *(const bf16x8*)(albuf + a_addr[mi] + aoff);
            #pragma unroll
            for (int jj = 0; jj < 4; ++jj)
                bfr[jj] = *(const bf16x8*)(bb + b_addr[jj]);
            #pragma unroll
            for (int mi = 0; mi < 8; ++mi)
                #pragma unroll
                for (int jj = 0; jj < 4; ++jj)
                    acc[mi][jj] = __builtin_amdgcn_mfma_f32_16x16x32_bf16(
                        af[mi], bfr[jj], acc[mi][jj], 0, 0, 0);

            __syncthreads();     // drains vmcnt: next B landed; buf reads done
            cur ^= 1;
        }
        if (ck < 7) {
            stageA(ck + 1);      // albuf reads finished at stage-end barrier
            __syncthreads();
        }
    }

    // ---- epilogue ----
    int quad = L >> 4;
    int wbase = wv * 64;
    #pragma unroll
    for (int jj = 0; jj < 4; ++jj) {
        int co = wbase + jj*16 + (L & 15);
        float s_ = g[co] * rsqrtf(vv[co] + EPSV);
        float t_ = b[co] - mu[co] * s_;
        #pragma unroll
        for (int mi = 0; mi < 8; ++mi) {
            int pbase = mi*16 + quad*4;       // pixel 0..127
            int sub   = pbase >> 6;           // compile-time per mi
            int pl    = pbase & 63;
            int yy = sub ? y0b : y0a;
            int xx = sub ? x0b : x0a;
            size_t ib = sub ? ibaseb : ibasea;
            int nn = sub ? n1 : n0;
            if (FIRST) {
                #pragma unroll
                for (int r = 0; r < 4; ++r) {
                    int p = pl + r;
                    float v = acc[mi][jj][r] * s_ + t_;
                    v = fmaxf(v, 0.f) * msk[pbase + r];
                    int pg = (yy + (p >> 3))*W + (xx + (p & 7));
                    outb[ib + (size_t)pg*C + co] = __float2bfloat16(v);
                }
            } else {
                int pg = (yy + (pl >> 3))*W + (xx + (pl & 7));
                size_t oidx = ((size_t)(nn*C + co))*HW + pg;
                floatx4 xr = *(const floatx4*)(xres + oidx);
                floatx4 ov;
                #pragma unroll
                for (int r = 0; r < 4; ++r) {
                    float v = acc[mi][jj][r] * s_ + t_;
                    v = v * msk[pbase + r] + xr[r];
                    ov[r] = fmaxf(v, 0.f);
                }
                *(floatx4*)(outf + oidx) = ov;
            }
        }
    }
}

extern "C" void kernel_launch(void* const* d_in, const int* in_sizes, int n_in,
                              void* d_out, int out_size, void* d_ws, size_t ws_size,
                              hipStream_t stream) {
    const float* x   = (const float*)d_in[0];
    const float* w1  = (const float*)d_in[1];
    const float* w2  = (const float*)d_in[2];
    const float* g1  = (const float*)d_in[3];
    const float* b1  = (const float*)d_in[4];
    const float* mu1 = (const float*)d_in[5];
    const float* v1  = (const float*)d_in[6];
    const float* g2  = (const float*)d_in[7];
    const float* b2  = (const float*)d_in[8];
    const float* mu2 = (const float*)d_in[9];
    const float* v2  = (const float*)d_in[10];
    const float* wm1 = (const float*)d_in[11];
    const float* bm1 = (const float*)d_in[12];
    const float* wm2 = (const float*)d_in[13];
    const float* bm2 = (const float*)d_in[14];
    float* out = (float*)d_out;

    // workspace (~83.5 MB):
    float* m1   = (float*)d_ws;                      // NB*HW
    float* m2   = m1 + (size_t)NBHW;                 // NB*HW
    bf16*  w1p  = (bf16*)(m2 + (size_t)NBHW);        // WELEM
    bf16*  w2p  = w1p + WELEM;                       // WELEM
    bf16*  tmpb = w2p + WELEM;                       // NB*HW*C bf16
    double* z   = (double*)(tmpb + (size_t)NBHW*C);  // MSPL*2*9*NBHW f64 = 28.9 MB
    double* wd  = z + (size_t)MSPL*18*NBHW;          // C*18 f64
    // xb (NHWC bf16, 51.4 MB) lives in d_out: dead until conv2's epilogue.
    bf16*  xb   = (bf16*)d_out;

    wcvt_kernel<<<(C*18 + 127)/128, 128, 0, stream>>>(wm1, wm2, wd);
    mask_part_kernel<<<(NBHW/128)*MSPL, 128, 0, stream>>>(x, wd, z);
    mask_reduce_kernel<<<NBHW/256, 256, 0, stream>>>(z, bm1, bm2, m1, m2);
    transpose_kernel<<<NB*4*49, 256, 0, stream>>>(x, xb);
    pack_kernel<<<2*WELEM/256, 256, 0, stream>>>(w1, w2, w1p, w2p);

    const int grid = NBHW / 128;    // 784 blocks: two 8x8 subtiles x full co
    conv_mfma<true ><<<grid, 256, 0, stream>>>(
        xb,   w1p, g1, b1, mu1, v1, m1, nullptr, tmpb, nullptr);
    conv_mfma<false><<<grid, 256, 0, stream>>>(
        tmpb, w2p, g2, b2, mu2, v2, m2, x, nullptr, out);
}

// Round 7
// 543.279 us; speedup vs baseline: 1.2592x; 1.1101x over previous
//
#include <hip/hip_runtime.h>
#include <hip/hip_bf16.h>

// ScaleNet gated residual block, MI355X — bf16 MFMA implicit GEMM.
//  K0w wcvt       : mask weights f32 -> f64, layout [c][mask(2)][tap(9)]
//  K0a mask_part  : tap-decomposed channel reduction -> z partials (f64, ws)
//  K0b mask_reduce: 9-point stencil sum of z + bias, threshold -> m1, m2
//  K1 transpose   : x NCHW f32 -> xb NHWC bf16 (stored in d_out scratch)
//  K2 pack        : w1,w2 OIHW f32 -> B-frag-ready packed bf16
//  K3 conv_mfma<1>: conv1 + BN1 + ReLU + *m1 -> tmp NHWC bf16 (ws)
//  K4 conv_mfma<0>: conv2 + BN2 + *m2 + residual + ReLU -> d_out NCHW f32
//
// R7: R6 hit the documented 2-phase ceiling (MfmaUtil 23.6% ~= m233's 24%).
//     B panels are PER-WAVE PRIVATE -> per-tap barriers removed entirely.
//     3-slot private LDS circular buffer, DMA issued 2 taps ahead, counted
//     s_waitcnt vmcnt(8) (never 0). Barriers only around stageA (16 total).
//     setprio(1) around MFMA cluster (waves now drift -> role diversity).

#define NB 32
#define C  256
#define H  56
#define W  56
#define HW (H*W)          // 3136 = 49*64
#define NBHW (NB*HW)      // 100352
#define EPSV 1e-5f
#define WELEM (C*C*9)     // 589824 packed elements per conv
#define MSPL 2            // mask split-K over channels
#define MCH (C/MSPL)      // 128 channels per split

typedef __hip_bfloat16 bf16;
typedef __attribute__((ext_vector_type(8))) short  bf16x8;
typedef __attribute__((ext_vector_type(4))) float  floatx4;

// async 16B/lane global->LDS DMA: lds gets wave-uniform base + lane*16
__device__ __forceinline__ void async_copy16(void* lds, const void* gptr) {
    __builtin_amdgcn_global_load_lds(
        (const __attribute__((address_space(1))) unsigned int*)gptr,
        (__attribute__((address_space(3))) unsigned int*)lds, 16, 0, 0);
}

// ---------------- K0w: mask weights f32 -> f64 ------------------------------
__global__ __launch_bounds__(128) void wcvt_kernel(
    const float* __restrict__ wm1, const float* __restrict__ wm2,
    double* __restrict__ wd)
{
    int i = blockIdx.x * 128 + threadIdx.x;   // 0 .. C*18-1
    if (i >= C * 18) return;
    int c = i / 18;
    int r = i - c * 18;
    int m = r / 9;
    int t = r - 9 * m;
    const float* src = m ? wm2 : wm1;
    wd[i] = (double)src[c * 9 + t];
}

// ---------------- K0a: tap-decomposed mask partials -------------------------
__global__ __launch_bounds__(128) void mask_part_kernel(
    const float* __restrict__ x, const double* __restrict__ wd,
    double* __restrict__ z)
{
    int pixb  = blockIdx.x >> 1;              // 784 pixel-blocks of 128
    int split = blockIdx.x & 1;
    int idx = pixb * 128 + threadIdx.x;       // pixel id, exact (100352 total)
    int n  = idx / HW;
    int hw = idx - n * HW;

    const float*  xp = x  + (size_t)n * C * HW + (size_t)split * MCH * HW + hw;
    const double* wp = wd + (size_t)split * MCH * 18;

    double acc[18];
    #pragma unroll
    for (int j = 0; j < 18; ++j) acc[j] = 0.0;

    for (int c = 0; c < MCH; ++c) {
        double xv = (double)xp[(size_t)c * HW];   // coalesced across lanes
        const double* w = wp + c * 18;            // wave-uniform -> s_load
        #pragma unroll
        for (int j = 0; j < 18; ++j)
            acc[j] += xv * w[j];
    }

    #pragma unroll
    for (int j = 0; j < 18; ++j)
        z[(size_t)(split * 18 + j) * NBHW + idx] = acc[j];
}

// ---------------- K0b: stencil-sum partials, threshold ----------------------
__global__ __launch_bounds__(256) void mask_reduce_kernel(
    const double* __restrict__ z,
    const float* __restrict__ bm1, const float* __restrict__ bm2,
    float* __restrict__ m1, float* __restrict__ m2)
{
    int idx = blockIdx.x * 256 + threadIdx.x;
    int n  = idx / HW;
    int hw = idx - n * HW;
    int h  = hw / W;
    int w_ = hw - h * W;

    double a1 = (double)bm1[0], a2 = (double)bm2[0];
    #pragma unroll
    for (int ky = 0; ky < 3; ++ky) {
        int y = h + ky - 1;
        if ((unsigned)y >= (unsigned)H) continue;
        #pragma unroll
        for (int kx = 0; kx < 3; ++kx) {
            int xx = w_ + kx - 1;
            if ((unsigned)xx >= (unsigned)W) continue;
            int t = ky * 3 + kx;
            size_t q = (size_t)n * HW + (size_t)y * W + xx;
            a1 += z[(size_t)(0 * 18 + 0 * 9 + t) * NBHW + q]
                + z[(size_t)(1 * 18 + 0 * 9 + t) * NBHW + q];
            a2 += z[(size_t)(0 * 18 + 1 * 9 + t) * NBHW + q]
                + z[(size_t)(1 * 18 + 1 * 9 + t) * NBHW + q];
        }
    }
    m1[idx] = (a1 > 0.0) ? 1.0f : 0.0f;   // sigmoid(z)>0.5 <=> z>0
    m2[idx] = (a2 > 0.0) ? 1.0f : 0.0f;
}

// ---------------- K1: NCHW f32 -> NHWC bf16 ---------------------------------
__global__ __launch_bounds__(256) void transpose_kernel(
    const float* __restrict__ x, bf16* __restrict__ xb)
{
    __shared__ float tile[64][65];
    int bid = blockIdx.x;             // 32 * 4 * 49
    int pt = bid % 49; bid /= 49;
    int ct = bid % 4;  int n = bid / 4;
    int p0 = pt * 64, c0 = ct * 64;
    int tl = threadIdx.x & 63;
    int tg = threadIdx.x >> 6;        // 0..3
    const float* xp = x + ((size_t)(n*C + c0) * HW) + p0;
    #pragma unroll
    for (int i = 0; i < 16; ++i) {
        int cl = tg*16 + i;
        tile[cl][tl] = xp[(size_t)cl * HW + tl];
    }
    __syncthreads();
    bf16* op = xb + ((size_t)(n*HW + p0) * C) + c0;
    #pragma unroll
    for (int i = 0; i < 16; ++i) {
        int pl = tg*16 + i;
        op[(size_t)pl * C + tl] = __float2bfloat16(tile[tl][pl]);
    }
}

// ---------------- K2: pack weights into B-frag order ------------------------
// layout: [tap(9)][kstep(8)][ntile(16)][lane(64)][8 ci]  (16B per lane)
__global__ __launch_bounds__(256) void pack_kernel(
    const float* __restrict__ w1, const float* __restrict__ w2,
    bf16* __restrict__ w1p, bf16* __restrict__ w2p)
{
    int idx = blockIdx.x * 256 + threadIdx.x;       // 0 .. 2*WELEM-1
    const float* src = (idx < WELEM) ? w1 : w2;
    bf16* dst        = (idx < WELEM) ? w1p : w2p;
    int f = (idx < WELEM) ? idx : idx - WELEM;
    int e  = f & 7;
    int O  = f >> 3;
    int L  = O & 63;
    int j  = (O >> 6) & 15;
    int ks = (O >> 10) & 7;
    int t  = O >> 13;
    int co = j*16 + (L & 15);
    int ci = ks*32 + ((L >> 4) & 3)*8 + e;
    dst[f] = __float2bfloat16(src[((size_t)co*C + ci)*9 + t]);
}

// ---------------- K3/K4: MFMA implicit-GEMM conv ----------------------------
// 256 thr / 4 waves; 128 px (two 8x8 subtiles) x 256 co per block.
// K = 8 ci-chunks x 9 taps. A patch staged cooperatively per ck (barrier
// pair). Within a ck the 9 taps run BARRIER-FREE per wave: B panels are
// per-wave private (wave wv only reads co-tiles wv*4..wv*4+3), staged into
// a 3-slot private LDS circular buffer via global_load_lds issued 2 taps
// ahead, synchronized by counted s_waitcnt vmcnt(8) (never 0 in the loop).
template<bool FIRST>
__global__ __launch_bounds__(256, 2) void conv_mfma(
    const bf16* __restrict__ inb,    // NHWC bf16
    const bf16* __restrict__ wp,     // packed weights
    const float* __restrict__ g,  const float* __restrict__ b,
    const float* __restrict__ mu, const float* __restrict__ vv,
    const float* __restrict__ mask,  // [NB][HW] 0/1
    const float* __restrict__ xres,  // NCHW f32 (SECOND)
    bf16* __restrict__ outb,         // FIRST: tmp NHWC bf16
    float* __restrict__ outf)        // SECOND: NCHW f32
{
    __shared__ uint4 albufq[800];        // A granules: 12.8 KB
    __shared__ uint4 bbufq[3*1024];      // B: 3 slots x 4 waves x 4 KB = 48 KB
    __shared__ float msk[128];
    short* albuf = (short*)albufq;
    short* bbuf  = (short*)bbufq;

    int tid = threadIdx.x;
    int L   = tid & 63;
    int wv  = tid >> 6;              // 0..3 co-group

    int bid = (int)blockIdx.x;
    bid = (bid & 7) * 98 + (bid >> 3);   // XCD-chunked swizzle (784 = 8*98)

    int t0g = bid * 2;
    int n0 = t0g / 49, tl0 = t0g - n0 * 49;
    int y0a = (tl0 / 7) * 8, x0a = (tl0 % 7) * 8;
    size_t ibasea = (size_t)n0 * HW * C;
    int t1g = t0g + 1;
    int n1 = t1g / 49, tl1 = t1g - n1 * 49;
    int y0b = (tl1 / 7) * 8, x0b = (tl1 % 7) * 8;
    size_t ibaseb = (size_t)n1 * HW * C;

    if (tid < 128) {
        int s  = tid >> 6;
        int p  = tid & 63;
        int pr = p >> 3, pc = p & 7;
        int nn = s ? n1  : n0;
        int yy = s ? y0b : y0a;
        int xx = s ? x0b : x0a;
        msk[tid] = mask[(size_t)nn*HW + (yy+pr)*W + (xx+pc)];
    }

    // A-frag base addresses (shorts): granule (kb, pos2), tap adds dt granules
    int m  = L & 15;
    int kb = L >> 4;
    int a_addr[8];
    #pragma unroll
    for (int mi = 0; mi < 8; ++mi) {
        int p    = mi*16 + m;            // 0..127
        int sub  = p >> 6;
        int pl   = p & 63;
        int pos2 = sub*100 + (pl >> 3)*10 + (pl & 7);
        a_addr[mi] = (kb*200 + pos2) * 8;
    }
    // per-wave private B region base (shorts): slot adds slot*4*2048
    int b_base = wv*2048 + L*8;

    floatx4 acc[8][4];
    #pragma unroll
    for (int mi = 0; mi < 8; ++mi)
        #pragma unroll
        for (int jj = 0; jj < 4; ++jj)
            acc[mi][jj] = (floatx4){0.f, 0.f, 0.f, 0.f};

    // ---- staging helpers ----
    auto stageA = [&](int ck) {
        for (int S = tid; S < 800; S += 256) {
            int kbg  = S / 200;              // ci granule 0..3
            int pos2 = S - kbg*200;
            int sub  = pos2 >= 100;
            int pos  = sub ? pos2 - 100 : pos2;
            int r  = pos / 10;
            int c  = pos - r*10;
            int yy = (sub ? y0b : y0a) + r - 1;
            int xx = (sub ? x0b : x0a) + c - 1;
            uint4 val = make_uint4(0u, 0u, 0u, 0u);
            if ((unsigned)yy < (unsigned)H && (unsigned)xx < (unsigned)W) {
                size_t ib = sub ? ibaseb : ibasea;
                val = *(const uint4*)(inb + ib + (size_t)(yy*W + xx)*C + ck*32 + kbg*8);
            }
            albufq[S] = val;
        }
    };
    // DMA this wave's private 4 KB B panel for (tap2, ck2) into slot
    auto issueB = [&](int tap2, int ck2, int slot) {
        const bf16* src = wp + (size_t)(tap2*8 + ck2) * 8192 + (size_t)wv*4*512 + L*8;
        short* dstb = bbuf + (slot*4 + wv)*2048;
        #pragma unroll
        for (int i = 0; i < 4; ++i)
            async_copy16(dstb + i*512, src + i*512);
    };

    // prologue: A for ck0; B for (tap0,ck0)->slot0, (tap1,ck0)->slot1
    stageA(0);
    issueB(0, 0, 0);
    issueB(1, 0, 1);
    __syncthreads();          // drains vmcnt: slots 0,1 landed; albuf visible

    for (int ck = 0; ck < 8; ++ck) {
        #pragma unroll
        for (int tap = 0; tap < 9; ++tap) {
            // issue B two taps ahead (per-wave private; crosses ck boundary)
            if (tap < 7) {
                issueB(tap + 2, ck, (tap + 2) % 3);
            } else {
                if (ck < 7) issueB(tap - 7, ck + 1, (tap - 7) % 3);
            }
            // counted wait: tap's slot (issued 2 taps ago) has landed;
            // up to 8 newer DMAs stay in flight across this point.
            __builtin_amdgcn_sched_barrier(0);
            asm volatile("s_waitcnt vmcnt(8)" ::: "memory");
            __builtin_amdgcn_sched_barrier(0);

            const int ky = tap / 3;
            const int aoff = (ky*10 + (tap - ky*3)) * 8;   // dt granules -> shorts
            const int bslot = (tap % 3) * 4 * 2048;
            bf16x8 af[8], bfr[4];
            #pragma unroll
            for (int mi = 0; mi < 8; ++mi)
                af[mi] = *(const bf16x8*)(albuf + a_addr[mi] + aoff);
            #pragma unroll
            for (int jj = 0; jj < 4; ++jj)
                bfr[jj] = *(const bf16x8*)(bbuf + bslot + b_base + jj*512);
            __builtin_amdgcn_s_setprio(1);
            #pragma unroll
            for (int mi = 0; mi < 8; ++mi)
                #pragma unroll
                for (int jj = 0; jj < 4; ++jj)
                    acc[mi][jj] = __builtin_amdgcn_mfma_f32_16x16x32_bf16(
                        af[mi], bfr[jj], acc[mi][jj], 0, 0, 0);
            __builtin_amdgcn_s_setprio(0);
        }
        if (ck < 7) {
            __syncthreads();     // all waves done reading albuf (and slots 0,1 landed)
            stageA(ck + 1);
            __syncthreads();     // albuf(ck+1) visible
        }
    }

    // ---- epilogue ----
    int quad = L >> 4;
    int wbase = wv * 64;
    #pragma unroll
    for (int jj = 0; jj < 4; ++jj) {
        int co = wbase + jj*16 + (L & 15);
        float s_ = g[co] * rsqrtf(vv[co] + EPSV);
        float t_ = b[co] - mu[co] * s_;
        #pragma unroll
        for (int mi = 0; mi < 8; ++mi) {
            int pbase = mi*16 + quad*4;       // pixel 0..127
            int sub   = pbase >> 6;           // compile-time per mi
            int pl    = pbase & 63;
            int yy = sub ? y0b : y0a;
            int xx = sub ? x0b : x0a;
            size_t ib = sub ? ibaseb : ibasea;
            int nn = sub ? n1 : n0;
            if (FIRST) {
                #pragma unroll
                for (int r = 0; r < 4; ++r) {
                    int p = pl + r;
                    float v = acc[mi][jj][r] * s_ + t_;
                    v = fmaxf(v, 0.f) * msk[pbase + r];
                    int pg = (yy + (p >> 3))*W + (xx + (p & 7));
                    outb[ib + (size_t)pg*C + co] = __float2bfloat16(v);
                }
            } else {
                int pg = (yy + (pl >> 3))*W + (xx + (pl & 7));
                size_t oidx = ((size_t)(nn*C + co))*HW + pg;
                floatx4 xr = *(const floatx4*)(xres + oidx);
                floatx4 ov;
                #pragma unroll
                for (int r = 0; r < 4; ++r) {
                    float v = acc[mi][jj][r] * s_ + t_;
                    v = v * msk[pbase + r] + xr[r];
                    ov[r] = fmaxf(v, 0.f);
                }
                *(floatx4*)(outf + oidx) = ov;
            }
        }
    }
}

extern "C" void kernel_launch(void* const* d_in, const int* in_sizes, int n_in,
                              void* d_out, int out_size, void* d_ws, size_t ws_size,
                              hipStream_t stream) {
    const float* x   = (const float*)d_in[0];
    const float* w1  = (const float*)d_in[1];
    const float* w2  = (const float*)d_in[2];
    const float* g1  = (const float*)d_in[3];
    const float* b1  = (const float*)d_in[4];
    const float* mu1 = (const float*)d_in[5];
    const float* v1  = (const float*)d_in[6];
    const float* g2  = (const float*)d_in[7];
    const float* b2  = (const float*)d_in[8];
    const float* mu2 = (const float*)d_in[9];
    const float* v2  = (const float*)d_in[10];
    const float* wm1 = (const float*)d_in[11];
    const float* bm1 = (const float*)d_in[12];
    const float* wm2 = (const float*)d_in[13];
    const float* bm2 = (const float*)d_in[14];
    float* out = (float*)d_out;

    // workspace (~83.5 MB):
    float* m1   = (float*)d_ws;                      // NB*HW
    float* m2   = m1 + (size_t)NBHW;                 // NB*HW
    bf16*  w1p  = (bf16*)(m2 + (size_t)NBHW);        // WELEM
    bf16*  w2p  = w1p + WELEM;                       // WELEM
    bf16*  tmpb = w2p + WELEM;                       // NB*HW*C bf16
    double* z   = (double*)(tmpb + (size_t)NBHW*C);  // MSPL*2*9*NBHW f64 = 28.9 MB
    double* wd  = z + (size_t)MSPL*18*NBHW;          // C*18 f64
    // xb (NHWC bf16, 51.4 MB) lives in d_out: dead until conv2's epilogue.
    bf16*  xb   = (bf16*)d_out;

    wcvt_kernel<<<(C*18 + 127)/128, 128, 0, stream>>>(wm1, wm2, wd);
    mask_part_kernel<<<(NBHW/128)*MSPL, 128, 0, stream>>>(x, wd, z);
    mask_reduce_kernel<<<NBHW/256, 256, 0, stream>>>(z, bm1, bm2, m1, m2);
    transpose_kernel<<<NB*4*49, 256, 0, stream>>>(x, xb);
    pack_kernel<<<2*WELEM/256, 256, 0, stream>>>(w1, w2, w1p, w2p);

    const int grid = NBHW / 128;    // 784 blocks: two 8x8 subtiles x full co
    conv_mfma<true ><<<grid, 256, 0, stream>>>(
        xb,   w1p, g1, b1, mu1, v1, m1, nullptr, tmpb, nullptr);
    conv_mfma<false><<<grid, 256, 0, stream>>>(
        tmpb, w2p, g2, b2, mu2, v2, m2, x, nullptr, out);
}